// Round 1
// baseline (7057.446 us; speedup 1.0000x reference)
//
#include <hip/hip_runtime.h>
#include <math.h>

#define NTS 12
#define NND 2048
#define NED 32768
#define XDI 128
#define HDI 256
#define H2I 512
#define ZDI 32
#define EPSC 1e-10f

// ---------------- device helpers ----------------

__device__ __forceinline__ float lsigf(float x) {
    // log_sigmoid(x) = min(x,0) - log1p(exp(-|x|))
    return fminf(x, 0.f) - log1pf(expf(-fabsf(x)));
}

template <int ACT>
__device__ __forceinline__ float actf(float v) {
    if (ACT == 1) return fmaxf(v, 0.f);                                // relu
    if (ACT == 2) return 1.f / (1.f + expf(-v));                       // sigmoid
    if (ACT == 3) return tanhf(v);                                     // tanh
    if (ACT == 4) return fmaxf(v, 0.f) + log1pf(expf(-fabsf(v)));      // softplus
    return v;
}

// ---------------- CSR build ----------------

__global__ void count_kernel(const int* __restrict__ dst, int* __restrict__ counts) {
    int e = blockIdx.x * 256 + threadIdx.x;
    if (e < NED) atomicAdd(&counts[dst[e]], 1);
}

// single block, 256 threads: exclusive scan of counts[2048] -> offsets[2049], deg, dinv
__global__ void scan_kernel(const int* __restrict__ counts, int* __restrict__ offsets,
                            float* __restrict__ deg, float* __restrict__ dinv) {
    __shared__ int tsum[256];
    int tid = threadIdx.x;
    int base = tid * 8;
    int local[8];
    int s = 0;
    for (int i = 0; i < 8; i++) { local[i] = s; s += counts[base + i]; }
    tsum[tid] = s;
    __syncthreads();
    for (int offp = 1; offp < 256; offp <<= 1) {
        int v = (tid >= offp) ? tsum[tid - offp] : 0;
        __syncthreads();
        tsum[tid] += v;
        __syncthreads();
    }
    int excl = tsum[tid] - s;
    for (int i = 0; i < 8; i++) offsets[base + i] = excl + local[i];
    if (tid == 255) offsets[NND] = excl + s;
    for (int i = 0; i < 8; i++) {
        float d = (float)counts[base + i] + 1.0f;
        deg[base + i] = d;
        dinv[base + i] = 1.0f / sqrtf(d);
    }
}

__global__ void fill_kernel(const int* __restrict__ src, const int* __restrict__ dst,
                            const int* __restrict__ offsets, int* __restrict__ cursor,
                            const float* __restrict__ dinv,
                            int* __restrict__ csrc, float* __restrict__ csrw) {
    int e = blockIdx.x * 256 + threadIdx.x;
    if (e < NED) {
        int d = dst[e];
        int s = src[e];
        int pos = offsets[d] + atomicAdd(&cursor[d], 1);
        csrc[pos] = s;
        csrw[pos] = dinv[s] * dinv[d];
    }
}

// ---------------- GIN gather: out[n] = x[n] + sum_{src->n} x[src] ----------------
// x is inA (D=256) or the concat [inA, inB] (each 256 wide) if two!=0.
__global__ __launch_bounds__(256) void gin_gather(const float* __restrict__ inA,
                                                  const float* __restrict__ inB,
                                                  const int* __restrict__ offsets,
                                                  const int* __restrict__ csrc,
                                                  float* __restrict__ out, int two) {
    int n = blockIdx.x;
    int tid = threadIdx.x;
    int e0 = offsets[n], e1 = offsets[n + 1];
    float a = inA[(size_t)n * HDI + tid];
    float b = two ? inB[(size_t)n * HDI + tid] : 0.f;
    for (int j = e0; j < e1; j++) {
        int s = csrc[j];
        a += inA[(size_t)s * HDI + tid];
        if (two) b += inB[(size_t)s * HDI + tid];
    }
    if (two) {
        out[(size_t)n * H2I + tid] = a;
        out[(size_t)n * H2I + HDI + tid] = b;
    } else {
        out[(size_t)n * HDI + tid] = a;
    }
}

// ---------------- GCN: out[n,m] = sum_e w_e*xw[src_e,m] + xw[n,m]/deg[n] + b[m] ----------------
__global__ void gcn_kernel(const float* __restrict__ xw, const float* __restrict__ b,
                           const int* __restrict__ offsets, const int* __restrict__ csrc,
                           const float* __restrict__ csrw, const float* __restrict__ deg,
                           float* __restrict__ out) {
    int half = threadIdx.x >> 5;
    int m = threadIdx.x & 31;
    int n = blockIdx.x * 2 + half;
    int e0 = offsets[n], e1 = offsets[n + 1];
    float acc = 0.f;
    for (int j = e0; j < e1; j++) acc += csrw[j] * xw[(size_t)csrc[j] * ZDI + m];
    out[(size_t)n * ZDI + m] = acc + xw[(size_t)n * ZDI + m] / deg[n] + b[m];
}

// ---------------- big GEMM: C[2048,M] = act(A1[2048,K1]@B1 + A2@B2 + bias) ----------------
template <int ACT, bool HAS_A2, bool HAS_BIAS>
__global__ __launch_bounds__(256) void gemm64(const float* __restrict__ A1,
                                              const float* __restrict__ B1, int K1,
                                              const float* __restrict__ A2,
                                              const float* __restrict__ B2, int K2,
                                              const float* __restrict__ bias,
                                              float* __restrict__ C, int M) {
    __shared__ float As[16][68];
    __shared__ float Bs[16][68];
    const int tid = threadIdx.x;
    const int tx = tid & 15, ty = tid >> 4;
    const int r0 = blockIdx.y * 64, c0 = blockIdx.x * 64;
    const int lrow = tid >> 2;        // 0..63
    const int lk = (tid & 3) * 4;     // 0,4,8,12
    const int brow = tid >> 4;        // 0..15
    const int bcol = (tid & 15) * 4;  // 0..60
    float acc[4][4] = {};

    const int npass = HAS_A2 ? 2 : 1;
    for (int pass = 0; pass < npass; ++pass) {
        const float* A = pass ? A2 : A1;
        const float* B = pass ? B2 : B1;
        const int K = pass ? K2 : K1;
        for (int k0 = 0; k0 < K; k0 += 16) {
            float4 av = *(const float4*)&A[(size_t)(r0 + lrow) * K + k0 + lk];
            float4 bv = *(const float4*)&B[(size_t)(k0 + brow) * M + c0 + bcol];
            __syncthreads();
            As[lk + 0][lrow] = av.x;
            As[lk + 1][lrow] = av.y;
            As[lk + 2][lrow] = av.z;
            As[lk + 3][lrow] = av.w;
            *(float4*)&Bs[brow][bcol] = bv;
            __syncthreads();
#pragma unroll
            for (int kk = 0; kk < 16; ++kk) {
                const float4 a4 = *(const float4*)&As[kk][ty * 4];
                const float4 b4 = *(const float4*)&Bs[kk][tx * 4];
                const float aa[4] = {a4.x, a4.y, a4.z, a4.w};
                const float bb[4] = {b4.x, b4.y, b4.z, b4.w};
#pragma unroll
                for (int i = 0; i < 4; i++)
#pragma unroll
                    for (int j = 0; j < 4; j++) acc[i][j] += aa[i] * bb[j];
            }
        }
    }

#pragma unroll
    for (int i = 0; i < 4; i++) {
        float4 v;
        float tmp[4];
#pragma unroll
        for (int j = 0; j < 4; j++) {
            float t = acc[i][j];
            if (HAS_BIAS) t += bias[c0 + tx * 4 + j];
            tmp[j] = actf<ACT>(t);
        }
        v.x = tmp[0]; v.y = tmp[1]; v.z = tmp[2]; v.w = tmp[3];
        *(float4*)&C[(size_t)(r0 + ty * 4 + i) * M + c0 + tx * 4] = v;
    }
}

// ---------------- small GEMM: C[2048,32] = act(A[2048,256]@B + bias) ----------------
template <int ACT, bool HAS_BIAS>
__global__ __launch_bounds__(256) void gemm_small(const float* __restrict__ A,
                                                  const float* __restrict__ B,
                                                  const float* __restrict__ bias,
                                                  float* __restrict__ C) {
    __shared__ float As[8][257];
    __shared__ float Bs[256 * 32];
    int tid = threadIdx.x;
    int n0 = blockIdx.x * 8;
    for (int idx = tid; idx < 8 * 256; idx += 256) {
        int r = idx >> 8, c = idx & 255;
        As[r][c] = A[(size_t)(n0 + r) * 256 + c];
    }
    for (int idx = tid; idx < 256 * 32; idx += 256) Bs[idx] = B[idx];
    __syncthreads();
    int r = tid >> 5, m = tid & 31;
    float acc = HAS_BIAS ? bias[m] : 0.f;
#pragma unroll 4
    for (int k = 0; k < 256; k++) acc += As[r][k] * Bs[k * 32 + m];
    C[(size_t)(n0 + r) * ZDI + m] = actf<ACT>(acc);
}

// ---------------- adj sum ----------------
__global__ void adj_sum_kernel(const float* __restrict__ a, double* __restrict__ ssum) {
    float s = 0.f;
    for (size_t i = (size_t)blockIdx.x * 256 + threadIdx.x; i < (size_t)NND * NND;
         i += (size_t)gridDim.x * 256)
        s += a[i];
    __shared__ float red[256];
    red[threadIdx.x] = s;
    __syncthreads();
    for (int o = 128; o > 0; o >>= 1) {
        if (threadIdx.x < o) red[threadIdx.x] += red[threadIdx.x + o];
        __syncthreads();
    }
    if (threadIdx.x == 0) atomicAdd(ssum, (double)red[0]);
}

// ---------------- z build: zcat[n, 0:32]=z_s, [32:64]=z_d ----------------
__global__ void z_kernel(const float* __restrict__ ms, const float* __restrict__ ss,
                         const float* __restrict__ es, const float* __restrict__ md,
                         const float* __restrict__ sd, const float* __restrict__ ed,
                         float* __restrict__ zcat) {
    int i = blockIdx.x * 256 + threadIdx.x;  // over N*Z
    int n = i >> 5, z = i & 31;
    zcat[(size_t)n * 64 + z] = ms[i] + ss[i] * es[i];
    zcat[(size_t)n * 64 + 32 + z] = md[i] + sd[i] * ed[i];
}

// ---------------- KLD accumulate ----------------
__global__ void kld_kernel(const float* __restrict__ m1, const float* __restrict__ s1,
                           const float* __restrict__ m2, const float* __restrict__ s2,
                           const float* __restrict__ n1, const float* __restrict__ t1,
                           const float* __restrict__ n2, const float* __restrict__ t2,
                           double* __restrict__ acc) {
    int i = blockIdx.x * 256 + threadIdx.x;  // over N*Z
    float v;
    {
        float a1 = s1[i] + EPSC, a2 = s2[i] + EPSC;
        float dm = m1[i] - m2[i];
        v = 2.f * (logf(a2) - logf(a1)) + (a1 * a1 + dm * dm) / (a2 * a2) - 1.f;
    }
    {
        float a1 = t1[i] + EPSC, a2 = t2[i] + EPSC;
        float dm = n1[i] - n2[i];
        v += 2.f * (logf(a2) - logf(a1)) + (a1 * a1 + dm * dm) / (a2 * a2) - 1.f;
    }
    __shared__ float red[256];
    red[threadIdx.x] = v;
    __syncthreads();
    for (int o = 128; o > 0; o >>= 1) {
        if (threadIdx.x < o) red[threadIdx.x] += red[threadIdx.x + o];
        __syncthreads();
    }
    if (threadIdx.x == 0) atomicAdd(acc, (double)red[0]);
}

// ---------------- dec = z_s @ z_d^T tile + store + BCE reduce ----------------
__global__ __launch_bounds__(256) void dec_bce_kernel(const float* __restrict__ zcat,
                                                      const float* __restrict__ adj,
                                                      const double* __restrict__ ssum,
                                                      float* __restrict__ dec,
                                                      double* __restrict__ nacc) {
    __shared__ float zsS[32][68];
    __shared__ float zdS[32][68];
    const int tid = threadIdx.x;
    const int tx = tid & 15, ty = tid >> 4;
    const int r0 = blockIdx.y * 64, c0 = blockIdx.x * 64;
    const int lrow = tid >> 2;       // 0..63
    const int lk = (tid & 3) * 8;    // 0,8,16,24

    float4 v0 = *(const float4*)&zcat[(size_t)(r0 + lrow) * 64 + lk];
    float4 v1 = *(const float4*)&zcat[(size_t)(r0 + lrow) * 64 + lk + 4];
    float4 w0 = *(const float4*)&zcat[(size_t)(c0 + lrow) * 64 + 32 + lk];
    float4 w1 = *(const float4*)&zcat[(size_t)(c0 + lrow) * 64 + 32 + lk + 4];
    zsS[lk + 0][lrow] = v0.x; zsS[lk + 1][lrow] = v0.y; zsS[lk + 2][lrow] = v0.z; zsS[lk + 3][lrow] = v0.w;
    zsS[lk + 4][lrow] = v1.x; zsS[lk + 5][lrow] = v1.y; zsS[lk + 6][lrow] = v1.z; zsS[lk + 7][lrow] = v1.w;
    zdS[lk + 0][lrow] = w0.x; zdS[lk + 1][lrow] = w0.y; zdS[lk + 2][lrow] = w0.z; zdS[lk + 3][lrow] = w0.w;
    zdS[lk + 4][lrow] = w1.x; zdS[lk + 5][lrow] = w1.y; zdS[lk + 6][lrow] = w1.z; zdS[lk + 7][lrow] = w1.w;
    __syncthreads();

    float acc[4][4] = {};
#pragma unroll
    for (int k = 0; k < 32; k++) {
        const float4 a4 = *(const float4*)&zsS[k][ty * 4];
        const float4 b4 = *(const float4*)&zdS[k][tx * 4];
        const float aa[4] = {a4.x, a4.y, a4.z, a4.w};
        const float bb[4] = {b4.x, b4.y, b4.z, b4.w};
#pragma unroll
        for (int i = 0; i < 4; i++)
#pragma unroll
            for (int j = 0; j < 4; j++) acc[i][j] += aa[i] * bb[j];
    }

    const float nn2 = 4194304.f;  // N*N
    float s = (float)(*ssum);
    float posw = (nn2 - s) / s;
    float norm = nn2 / ((nn2 - s) * 2.f);

    float bsum = 0.f;
#pragma unroll
    for (int i = 0; i < 4; i++) {
        int r = r0 + ty * 4 + i;
        const float4 av4 = *(const float4*)&adj[(size_t)r * NND + c0 + tx * 4];
        const float av[4] = {av4.x, av4.y, av4.z, av4.w};
        float* drow = &dec[(size_t)r * NND + c0 + tx * 4];
#pragma unroll
        for (int j = 0; j < 4; j++) {
            float d = acc[i][j];
            drow[j] = d;  // scalar store: dec base is d_out+2 (not 16B aligned)
            float a = av[j];
            bsum += -posw * a * lsigf(d) - (1.f - a) * lsigf(-d);
        }
    }
    __shared__ float red[256];
    red[tid] = bsum;
    __syncthreads();
    for (int o = 128; o > 0; o >>= 1) {
        if (tid < o) red[tid] += red[tid + o];
        __syncthreads();
    }
    if (tid == 0) atomicAdd(nacc, (double)norm * (double)red[0] / 4194304.0);
}

// ---------------- elementwise ----------------
__global__ void mul_kernel(const float* __restrict__ a, const float* __restrict__ b,
                           float* __restrict__ o) {
    size_t i = (size_t)blockIdx.x * 256 + threadIdx.x;
    o[i] = a[i] * b[i];
}

__global__ void gru_combine(const float* __restrict__ zg, const float* __restrict__ h,
                            const float* __restrict__ ht, float* __restrict__ nh) {
    size_t i = (size_t)blockIdx.x * 256 + threadIdx.x;
    float z = zg[i];
    nh[i] = z * h[i] + (1.f - z) * ht[i];
}

__global__ void finalize_kernel(const double* __restrict__ kacc, const double* __restrict__ nacc,
                                float* __restrict__ out) {
    if (threadIdx.x == 0 && blockIdx.x == 0) {
        out[0] = (float)(0.5 * (*kacc) / ((double)NND * (double)NND));
        out[1] = (float)(*nacc);
    }
}

// ---------------- host ----------------

extern "C" void kernel_launch(void* const* d_in, const int* in_sizes, int n_in,
                              void* d_out, int out_size, void* d_ws, size_t ws_size,
                              hipStream_t stream) {
    (void)in_sizes; (void)n_in; (void)out_size; (void)ws_size;

    const float* x_all = (const float*)d_in[0];
    const int* ei_all = (const int*)d_in[1];
    const float* adj_all = (const float*)d_in[2];
    const float* eps_s_all = (const float*)d_in[3];
    const float* eps_d_all = (const float*)d_in[4];
    const float* phi_x_w = (const float*)d_in[5];
    const float* phi_z_w = (const float*)d_in[6];
    const float* gru_xw0 = (const float*)d_in[7];
    const float* gru_xw1 = (const float*)d_in[8];
    const float* gru_hw = (const float*)d_in[9];
    const float* enc_w = (const float*)d_in[10];
    const float* enc_b = (const float*)d_in[11];
    const float* mean_w = (const float*)d_in[12];
    const float* mean_b = (const float*)d_in[13];
    const float* std_w = (const float*)d_in[14];
    const float* std_b = (const float*)d_in[15];
    const float* pri_w = (const float*)d_in[16];
    const float* pri_b = (const float*)d_in[17];
    const float* pri_mw = (const float*)d_in[18];
    const float* pri_mb = (const float*)d_in[19];
    const float* pri_sw = (const float*)d_in[20];
    const float* pri_sb = (const float*)d_in[21];
    float* out = (float*)d_out;

    // ---- workspace carve (~40 MB) ----
    size_t off = 0;
    auto alloc = [&](size_t bytes) -> void* {
        void* p = (char*)d_ws + off;
        off = (off + bytes + 255) & ~(size_t)255;
        return p;
    };
    const size_t NH = (size_t)NND * HDI;   // 524288
    const size_t NH2 = (size_t)NND * H2I;  // 1048576
    const size_t NZ = (size_t)NND * ZDI;   // 65536

    float* hbase = (float*)alloc(4 * NH * 4);  // [ping/pong][layer]
    float* phi_x = (float*)alloc(NH * 4);
    float* phi_z = (float*)alloc(NH * 4);
    float* enc_s = (float*)alloc(NH * 4);
    float* enc_d = (float*)alloc(NH * 4);
    float* ginA = (float*)alloc(NH * 4);
    float* ginB = (float*)alloc(NH * 4);
    float* zg = (float*)alloc(NH * 4);
    float* rg = (float*)alloc(NH * 4);
    float* htmp = (float*)alloc(NH * 4);
    float* cat_pre = (float*)alloc(NH2 * 4);
    float* xpre = (float*)alloc(NH2 * 4);
    float* zcat = (float*)alloc((size_t)NND * 64 * 4);
    float* xw_s = (float*)alloc(NZ * 4);
    float* xw_d = (float*)alloc(NZ * 4);
    float* mean_s = (float*)alloc(NZ * 4);
    float* mean_d = (float*)alloc(NZ * 4);
    float* std_s = (float*)alloc(NZ * 4);
    float* std_d = (float*)alloc(NZ * 4);
    float* pm_s = (float*)alloc(NZ * 4);
    float* ps_s = (float*)alloc(NZ * 4);
    float* pm_d = (float*)alloc(NZ * 4);
    float* ps_d = (float*)alloc(NZ * 4);
    float* deg = (float*)alloc(NND * 4);
    float* dinv = (float*)alloc(NND * 4);
    int* counts = (int*)alloc(2 * NND * 4);  // counts + cursor contiguous
    int* cursor = counts + NND;
    int* offsets = (int*)alloc((NND + 1) * 4);
    int* csrc = (int*)alloc(NED * 4);
    float* csrw = (float*)alloc(NED * 4);
    double* accd = (double*)alloc(4 * 8);  // [0]=kld, [1]=nll
    double* ssum = (double*)alloc(8);

    float* h0 = hbase;           // layer 0 current
    float* h1 = hbase + NH;      // layer 1 current
    float* nh0 = hbase + 2 * NH; // next
    float* nh1 = hbase + 3 * NH;

    hipMemsetAsync(hbase, 0, 2 * NH * 4, stream);  // h0, h1 = 0
    hipMemsetAsync(accd, 0, 2 * 8, stream);

    const dim3 gBig(HDI / 64, NND / 64);  // big gemm grid (M=256)
    const int HWg = (int)(NH / 256);       // elementwise grid

    for (int t = 0; t < NTS; ++t) {
        const float* x_t = x_all + (size_t)t * NND * XDI;
        const int* src = ei_all + (size_t)t * 2 * NED;
        const int* dst = src + NED;
        const float* adj_t = adj_all + (size_t)t * NND * NND;
        const float* es_t = eps_s_all + (size_t)t * NND * ZDI;
        const float* ed_t = eps_d_all + (size_t)t * NND * ZDI;
        float* dec_t = out + 2 + (size_t)t * NND * NND;

        // CSR build + degree
        hipMemsetAsync(counts, 0, 2 * NND * 4, stream);
        hipMemsetAsync(ssum, 0, 8, stream);
        count_kernel<<<NED / 256, 256, 0, stream>>>(dst, counts);
        scan_kernel<<<1, 256, 0, stream>>>(counts, offsets, deg, dinv);
        fill_kernel<<<NED / 256, 256, 0, stream>>>(src, dst, offsets, cursor, dinv, csrc, csrw);
        adj_sum_kernel<<<2048, 256, 0, stream>>>(adj_t, ssum);

        // phi_x = relu(x @ phi_x_w)
        gemm64<1, false, false><<<gBig, 256, 0, stream>>>(x_t, phi_x_w, XDI, nullptr, nullptr, 0,
                                                          nullptr, phi_x, HDI);
        // cat_pre = gin([phi_x, h1])
        gin_gather<<<NND, 256, 0, stream>>>(phi_x, h1, offsets, csrc, cat_pre, 1);
        // enc_s / enc_d
        gemm64<1, false, true><<<gBig, 256, 0, stream>>>(cat_pre, enc_w, H2I, nullptr, nullptr, 0,
                                                         enc_b, enc_s, HDI);
        gemm64<1, false, true><<<gBig, 256, 0, stream>>>(cat_pre, enc_w + (size_t)H2I * HDI, H2I,
                                                         nullptr, nullptr, 0, enc_b + HDI, enc_d, HDI);
        // mean via GCN
        gemm_small<0, false><<<NND / 8, 256, 0, stream>>>(enc_s, mean_w, nullptr, xw_s);
        gcn_kernel<<<NND / 2, 64, 0, stream>>>(xw_s, mean_b, offsets, csrc, csrw, deg, mean_s);
        gemm_small<0, false><<<NND / 8, 256, 0, stream>>>(enc_d, mean_w + (size_t)HDI * ZDI, nullptr, xw_d);
        gcn_kernel<<<NND / 2, 64, 0, stream>>>(xw_d, mean_b + ZDI, offsets, csrc, csrw, deg, mean_d);
        // std via GIN
        gin_gather<<<NND, 256, 0, stream>>>(enc_s, nullptr, offsets, csrc, ginA, 0);
        gemm_small<4, true><<<NND / 8, 256, 0, stream>>>(ginA, std_w, std_b, std_s);
        gin_gather<<<NND, 256, 0, stream>>>(enc_d, nullptr, offsets, csrc, ginB, 0);
        gemm_small<4, true><<<NND / 8, 256, 0, stream>>>(ginB, std_w + (size_t)HDI * ZDI, std_b + ZDI, std_d);
        // priors (zg/rg buffers reused as pri_s/pri_d)
        gemm64<1, false, true><<<gBig, 256, 0, stream>>>(h1, pri_w, HDI, nullptr, nullptr, 0,
                                                         pri_b, zg, HDI);
        gemm_small<0, true><<<NND / 8, 256, 0, stream>>>(zg, pri_mw, pri_mb, pm_s);
        gemm_small<4, true><<<NND / 8, 256, 0, stream>>>(zg, pri_sw, pri_sb, ps_s);
        gemm64<1, false, true><<<gBig, 256, 0, stream>>>(h1, pri_w + (size_t)HDI * HDI, HDI, nullptr,
                                                         nullptr, 0, pri_b + HDI, rg, HDI);
        gemm_small<0, true><<<NND / 8, 256, 0, stream>>>(rg, pri_mw + (size_t)HDI * ZDI, pri_mb + ZDI, pm_d);
        gemm_small<4, true><<<NND / 8, 256, 0, stream>>>(rg, pri_sw + (size_t)HDI * ZDI, pri_sb + ZDI, ps_d);
        // z, kld, phi_z, dec+bce
        z_kernel<<<(int)(NZ / 256), 256, 0, stream>>>(mean_s, std_s, es_t, mean_d, std_d, ed_t, zcat);
        kld_kernel<<<(int)(NZ / 256), 256, 0, stream>>>(mean_s, std_s, pm_s, ps_s, mean_d, std_d,
                                                        pm_d, ps_d, &accd[0]);
        gemm64<1, false, false><<<gBig, 256, 0, stream>>>(zcat, phi_z_w, 64, nullptr, nullptr, 0,
                                                          nullptr, phi_z, HDI);
        dec_bce_kernel<<<dim3(NND / 64, NND / 64), 256, 0, stream>>>(zcat, adj_t, ssum, dec_t, &accd[1]);

        // ---- GRU layer 0 ----
        gin_gather<<<NND, 256, 0, stream>>>(phi_x, phi_z, offsets, csrc, xpre, 1);
        gin_gather<<<NND, 256, 0, stream>>>(h0, nullptr, offsets, csrc, ginA, 0);
        gemm64<2, true, false><<<gBig, 256, 0, stream>>>(xpre, gru_xw0, H2I, ginA, gru_hw, HDI,
                                                         nullptr, zg, HDI);
        gemm64<2, true, false><<<gBig, 256, 0, stream>>>(xpre, gru_xw0 + (size_t)H2I * HDI, H2I, ginA,
                                                         gru_hw + (size_t)HDI * HDI, HDI, nullptr, rg, HDI);
        mul_kernel<<<HWg, 256, 0, stream>>>(rg, h0, htmp);
        gin_gather<<<NND, 256, 0, stream>>>(htmp, nullptr, offsets, csrc, ginB, 0);
        gemm64<3, true, false><<<gBig, 256, 0, stream>>>(xpre, gru_xw0 + 2 * (size_t)H2I * HDI, H2I,
                                                         ginB, gru_hw + 2 * (size_t)HDI * HDI, HDI,
                                                         nullptr, htmp, HDI);
        gru_combine<<<HWg, 256, 0, stream>>>(zg, h0, htmp, nh0);

        // ---- GRU layer 1 ----
        gin_gather<<<NND, 256, 0, stream>>>(nh0, nullptr, offsets, csrc, xpre, 0);
        gin_gather<<<NND, 256, 0, stream>>>(h1, nullptr, offsets, csrc, ginA, 0);
        gemm64<2, true, false><<<gBig, 256, 0, stream>>>(xpre, gru_xw1, HDI, ginA,
                                                         gru_hw + 3 * (size_t)HDI * HDI, HDI,
                                                         nullptr, zg, HDI);
        gemm64<2, true, false><<<gBig, 256, 0, stream>>>(xpre, gru_xw1 + (size_t)HDI * HDI, HDI, ginA,
                                                         gru_hw + 4 * (size_t)HDI * HDI, HDI,
                                                         nullptr, rg, HDI);
        mul_kernel<<<HWg, 256, 0, stream>>>(rg, h1, htmp);
        gin_gather<<<NND, 256, 0, stream>>>(htmp, nullptr, offsets, csrc, ginB, 0);
        gemm64<3, true, false><<<gBig, 256, 0, stream>>>(xpre, gru_xw1 + 2 * (size_t)HDI * HDI, HDI,
                                                         ginB, gru_hw + 5 * (size_t)HDI * HDI, HDI,
                                                         nullptr, htmp, HDI);
        gru_combine<<<HWg, 256, 0, stream>>>(zg, h1, htmp, nh1);

        // swap ping-pong
        float* tp;
        tp = h0; h0 = nh0; nh0 = tp;
        tp = h1; h1 = nh1; nh1 = tp;
    }

    finalize_kernel<<<1, 64, 0, stream>>>(&accd[0], &accd[1], out);
}

// Round 2
// 4190.931 us; speedup vs baseline: 1.6840x; 1.6840x over previous
//
#include <hip/hip_runtime.h>
#include <math.h>

#define NTS 12
#define NND 2048
#define NED 32768
#define XDI 128
#define HDI 256
#define H2I 512
#define ZDI 32
#define EPSC 1e-10f

// ---------------- device helpers ----------------

__device__ __forceinline__ float lsigf(float x) {
    // log_sigmoid(x) = min(x,0) - log1p(exp(-|x|))
    return fminf(x, 0.f) - log1pf(expf(-fabsf(x)));
}

template <int ACT>
__device__ __forceinline__ float actf(float v) {
    if (ACT == 1) return fmaxf(v, 0.f);                                // relu
    if (ACT == 2) return 1.f / (1.f + expf(-v));                       // sigmoid
    if (ACT == 3) return tanhf(v);                                     // tanh
    if (ACT == 4) return fmaxf(v, 0.f) + log1pf(expf(-fabsf(v)));      // softplus
    return v;
}

// ---------------- CSR build (all 12 timesteps upfront) ----------------

__global__ void count_all(const int* __restrict__ ei, int* __restrict__ counts) {
    int idx = blockIdx.x * 256 + threadIdx.x;   // 0 .. 12*NED-1
    int t = idx >> 15;                          // NED = 32768
    int e = idx & (NED - 1);
    const int* dst = ei + (size_t)t * 2 * NED + NED;
    atomicAdd(&counts[t * NND + dst[e]], 1);
}

// one block per timestep: exclusive scan of counts[2048] -> offsets[2049], deg, dinv
__global__ void scan_all(const int* __restrict__ counts, int* __restrict__ offsets,
                         float* __restrict__ deg, float* __restrict__ dinv) {
    int t = blockIdx.x;
    const int* cnt = counts + t * NND;
    int* off = offsets + t * (NND + 1);
    float* dg = deg + t * NND;
    float* dv = dinv + t * NND;
    __shared__ int tsum[256];
    int tid = threadIdx.x;
    int base = tid * 8;
    int local[8];
    int s = 0;
    for (int i = 0; i < 8; i++) { local[i] = s; s += cnt[base + i]; }
    tsum[tid] = s;
    __syncthreads();
    for (int offp = 1; offp < 256; offp <<= 1) {
        int v = (tid >= offp) ? tsum[tid - offp] : 0;
        __syncthreads();
        tsum[tid] += v;
        __syncthreads();
    }
    int excl = tsum[tid] - s;
    for (int i = 0; i < 8; i++) off[base + i] = excl + local[i];
    if (tid == 255) off[NND] = excl + s;
    for (int i = 0; i < 8; i++) {
        float d = (float)cnt[base + i] + 1.0f;
        dg[base + i] = d;
        dv[base + i] = 1.0f / sqrtf(d);
    }
}

__global__ void fill_all(const int* __restrict__ ei, const int* __restrict__ offsets,
                         int* __restrict__ cursor, const float* __restrict__ dinv,
                         int* __restrict__ csrc, float* __restrict__ csrw) {
    int idx = blockIdx.x * 256 + threadIdx.x;
    int t = idx >> 15;
    int e = idx & (NED - 1);
    const int* src = ei + (size_t)t * 2 * NED;
    const int* dst = src + NED;
    int d = dst[e], s = src[e];
    const int* off_t = offsets + t * (NND + 1);
    int pos = off_t[d] + atomicAdd(&cursor[t * NND + d], 1);
    csrc[(size_t)t * NED + pos] = s;
    csrw[(size_t)t * NED + pos] = dinv[t * NND + s] * dinv[t * NND + d];
}

// ---------------- multi-segment GIN gather ----------------
// out[seg][n] = in[seg][n] + sum_{src->n} in[seg][src]   (rows of 256 floats)
struct GatherArgs {
    const float* in[3];
    float* out[3];
    int ostr[3];
    int ooff[3];
};

__global__ __launch_bounds__(256) void gather_multi(GatherArgs ga,
                                                    const int* __restrict__ offsets,
                                                    const int* __restrict__ csrc) {
    int seg = blockIdx.y;
    const float* in = ga.in[seg];
    float* outp = ga.out[seg];
    int ostr = ga.ostr[seg], ooff = ga.ooff[seg];
    int ln = threadIdx.x >> 6;
    int lane = threadIdx.x & 63;
    int n = blockIdx.x * 4 + ln;
    int e0 = offsets[n], e1 = offsets[n + 1];
    int c4 = lane * 4;
    float4 a = *(const float4*)&in[(size_t)n * HDI + c4];
    int j = e0;
    for (; j + 1 < e1; j += 2) {
        int s0 = csrc[j], s1 = csrc[j + 1];
        float4 v0 = *(const float4*)&in[(size_t)s0 * HDI + c4];
        float4 v1 = *(const float4*)&in[(size_t)s1 * HDI + c4];
        a.x += v0.x + v1.x; a.y += v0.y + v1.y; a.z += v0.z + v1.z; a.w += v0.w + v1.w;
    }
    if (j < e1) {
        int s0 = csrc[j];
        float4 v0 = *(const float4*)&in[(size_t)s0 * HDI + c4];
        a.x += v0.x; a.y += v0.y; a.z += v0.z; a.w += v0.w;
    }
    *(float4*)&outp[(size_t)n * ostr + ooff + c4] = a;
}

// ---------------- GCN pair: out[n,m] = sum_e w_e*xw[src_e,m] + xw[n,m]/deg[n] + b[m] ----------------
__global__ void gcn_pair(const float* __restrict__ xwA, const float* __restrict__ xwB,
                         const float* __restrict__ bias2, const int* __restrict__ offsets,
                         const int* __restrict__ csrc, const float* __restrict__ csrw,
                         const float* __restrict__ deg, float* __restrict__ oA,
                         float* __restrict__ oB) {
    int sel = blockIdx.y;
    const float* xw = sel ? xwB : xwA;
    const float* b = bias2 + sel * ZDI;
    float* out = sel ? oB : oA;
    int n = blockIdx.x * 8 + (threadIdx.x >> 5);
    int m = threadIdx.x & 31;
    int e0 = offsets[n], e1 = offsets[n + 1];
    float acc = 0.f;
    for (int j = e0; j < e1; j++) acc += csrw[j] * xw[(size_t)csrc[j] * ZDI + m];
    out[(size_t)n * ZDI + m] = acc + xw[(size_t)n * ZDI + m] / deg[n] + b[m];
}

// ---------------- big GEMM (double-buffered, up to 2 outputs, fused epilogues) ----------------
// C[o] = epi(A1 @ B1[o] (+ A2 @ B2[o]) + bias[o]) ; all B have leading dim 256.
// EPI 0: act only.  EPI 1: act(sigmoid); output 1 multiplied by h.  EPI 2: nh = zg*h + (1-zg)*tanh(acc).
struct BigArgs {
    const float* A1; const float* A2;
    const float* B1[2]; const float* B2[2];
    const float* bias[2];
    float* C[2];
    const float* h; const float* zgp;
    int K1, K2;
};

template <int ACT, bool HAS_A2, bool HAS_BIAS, int EPI, bool TWO>
__global__ __launch_bounds__(256) void gemm_big(BigArgs g) {
    __shared__ float As[2][16][68];
    __shared__ float Bs[2][16][68];
    const int tid = threadIdx.x;
    const int tx = tid & 15, ty = tid >> 4;
    const int bx = blockIdx.x;
    const int outSel = TWO ? (bx >> 2) : 0;
    const int r0 = blockIdx.y * 64, c0 = (bx & 3) * 64;
    const float* B1 = g.B1[outSel];
    const float* B2 = HAS_A2 ? g.B2[outSel] : nullptr;

    const int lrow = tid >> 2;        // 0..63
    const int lk = (tid & 3) * 4;     // 0,4,8,12
    const int brow = tid >> 4;        // 0..15
    const int bcol = (tid & 15) * 4;  // 0..60

    const int nt1 = g.K1 >> 4;
    const int nt2 = HAS_A2 ? (g.K2 >> 4) : 0;
    const int nt = nt1 + nt2;

    auto loadTile = [&](int i, float4& av, float4& bv) {
        const float* A; const float* B; int K, k0;
        if (i < nt1) { A = g.A1; B = B1; K = g.K1; k0 = i * 16; }
        else { A = g.A2; B = B2; K = g.K2; k0 = (i - nt1) * 16; }
        av = *(const float4*)&A[(size_t)(r0 + lrow) * K + k0 + lk];
        bv = *(const float4*)&B[(size_t)(k0 + brow) * HDI + c0 + bcol];
    };

    float4 av, bv;
    loadTile(0, av, bv);
    As[0][lk + 0][lrow] = av.x; As[0][lk + 1][lrow] = av.y;
    As[0][lk + 2][lrow] = av.z; As[0][lk + 3][lrow] = av.w;
    *(float4*)&Bs[0][brow][bcol] = bv;

    float acc[4][4] = {};
    int buf = 0;
    for (int i = 0; i < nt; ++i) {
        __syncthreads();
        const bool more = (i + 1 < nt);
        if (more) loadTile(i + 1, av, bv);
#pragma unroll
        for (int kk = 0; kk < 16; ++kk) {
            const float4 a4 = *(const float4*)&As[buf][kk][ty * 4];
            const float4 b4 = *(const float4*)&Bs[buf][kk][tx * 4];
            const float aa[4] = {a4.x, a4.y, a4.z, a4.w};
            const float bb[4] = {b4.x, b4.y, b4.z, b4.w};
#pragma unroll
            for (int i2 = 0; i2 < 4; i2++)
#pragma unroll
                for (int j = 0; j < 4; j++) acc[i2][j] += aa[i2] * bb[j];
        }
        if (more) {
            const int nb = buf ^ 1;
            As[nb][lk + 0][lrow] = av.x; As[nb][lk + 1][lrow] = av.y;
            As[nb][lk + 2][lrow] = av.z; As[nb][lk + 3][lrow] = av.w;
            *(float4*)&Bs[nb][brow][bcol] = bv;
            buf = nb;
        }
    }

    float* C = g.C[outSel];
    const int colbase = c0 + tx * 4;
#pragma unroll
    for (int i = 0; i < 4; i++) {
        const int r = r0 + ty * 4 + i;
        float tmp[4];
        if (EPI == 2) {
            const float4 z4 = *(const float4*)&g.zgp[(size_t)r * HDI + colbase];
            const float4 h4 = *(const float4*)&g.h[(size_t)r * HDI + colbase];
            const float zz[4] = {z4.x, z4.y, z4.z, z4.w};
            const float hh[4] = {h4.x, h4.y, h4.z, h4.w};
#pragma unroll
            for (int j = 0; j < 4; j++) {
                float t = acc[i][j];
                if (HAS_BIAS) t += g.bias[outSel][colbase + j];
                tmp[j] = zz[j] * hh[j] + (1.f - zz[j]) * tanhf(t);
            }
        } else if (EPI == 1) {
            float hh[4] = {1.f, 1.f, 1.f, 1.f};
            if (outSel == 1) {
                const float4 h4 = *(const float4*)&g.h[(size_t)r * HDI + colbase];
                hh[0] = h4.x; hh[1] = h4.y; hh[2] = h4.z; hh[3] = h4.w;
            }
#pragma unroll
            for (int j = 0; j < 4; j++) {
                float t = acc[i][j];
                if (HAS_BIAS) t += g.bias[outSel][colbase + j];
                tmp[j] = actf<ACT>(t) * hh[j];
            }
        } else {
#pragma unroll
            for (int j = 0; j < 4; j++) {
                float t = acc[i][j];
                if (HAS_BIAS) t += g.bias[outSel][colbase + j];
                tmp[j] = actf<ACT>(t);
            }
        }
        float4 v; v.x = tmp[0]; v.y = tmp[1]; v.z = tmp[2]; v.w = tmp[3];
        *(float4*)&C[(size_t)r * HDI + colbase] = v;
    }
}

// ---------------- small GEMM batch: C = act(A[2048,256]@B[256,32] + bias) ----------------
struct SmallArgs {
    const float* A[4]; const float* B[4]; const float* bias[4];
    float* C[4]; int act[4];
};

__global__ __launch_bounds__(256) void small_gemm(SmallArgs s) {
    __shared__ float As[8][260];
    __shared__ float Bs[256 * 32];
    const int y = blockIdx.y;
    const float* A = s.A[y];
    const float* B = s.B[y];
    const float* bi = s.bias[y];
    float* C = s.C[y];
    const int act = s.act[y];
    const int tid = threadIdx.x;
    const int n0 = blockIdx.x * 8;
    for (int idx = tid; idx < 512; idx += 256) {
        int r = idx >> 6, c4 = (idx & 63) * 4;
        *(float4*)&As[r][c4] = *(const float4*)&A[(size_t)(n0 + r) * HDI + c4];
    }
    for (int idx = tid; idx < 2048; idx += 256)
        *(float4*)&Bs[idx * 4] = *(const float4*)&B[idx * 4];
    __syncthreads();
    const int r = tid >> 5, m = tid & 31;
    float acc = bi ? bi[m] : 0.f;
#pragma unroll 8
    for (int k = 0; k < 256; k++) acc += As[r][k] * Bs[k * 32 + m];
    if (act == 4) acc = fmaxf(acc, 0.f) + log1pf(expf(-fabsf(acc)));
    C[(size_t)(n0 + r) * ZDI + m] = acc;
}

// ---------------- z build + KLD fused ----------------
__global__ void zkld_kernel(const float* __restrict__ ms, const float* __restrict__ ss,
                            const float* __restrict__ es, const float* __restrict__ md,
                            const float* __restrict__ sd, const float* __restrict__ ed,
                            const float* __restrict__ pms, const float* __restrict__ pss,
                            const float* __restrict__ pmd, const float* __restrict__ psd,
                            float* __restrict__ zcat, double* __restrict__ kacc) {
    int i = blockIdx.x * 256 + threadIdx.x;  // over N*Z
    int n = i >> 5, z = i & 31;
    float m1 = ms[i], s1v = ss[i];
    float n1 = md[i], t1v = sd[i];
    zcat[(size_t)n * 64 + z] = m1 + s1v * es[i];
    zcat[(size_t)n * 64 + 32 + z] = n1 + t1v * ed[i];
    float v;
    {
        float a1 = s1v + EPSC, a2 = pss[i] + EPSC;
        float dm = m1 - pms[i];
        v = 2.f * (logf(a2) - logf(a1)) + (a1 * a1 + dm * dm) / (a2 * a2) - 1.f;
    }
    {
        float a1 = t1v + EPSC, a2 = psd[i] + EPSC;
        float dm = n1 - pmd[i];
        v += 2.f * (logf(a2) - logf(a1)) + (a1 * a1 + dm * dm) / (a2 * a2) - 1.f;
    }
    __shared__ float red[256];
    red[threadIdx.x] = v;
    __syncthreads();
    for (int o = 128; o > 0; o >>= 1) {
        if (threadIdx.x < o) red[threadIdx.x] += red[threadIdx.x + o];
        __syncthreads();
    }
    if (threadIdx.x == 0) atomicAdd(kacc, (double)red[0]);
}

// ---------------- dec = z_s @ z_d^T tile + store + BCE partial sums ----------------
// acc3: [0]=sum(adj), [1]=sum(adj*ls(d)), [2]=sum((1-adj)*ls(-d))
__global__ __launch_bounds__(256) void dec_bce(const float* __restrict__ zcat,
                                               const float* __restrict__ adj,
                                               float* __restrict__ dec,
                                               double* __restrict__ acc3) {
    __shared__ float zsS[32][68];
    __shared__ float zdS[32][68];
    const int tid = threadIdx.x;
    const int tx = tid & 15, ty = tid >> 4;
    const int r0 = blockIdx.y * 64, c0 = blockIdx.x * 64;
    const int lrow = tid >> 2;
    const int lk = (tid & 3) * 8;

    float4 v0 = *(const float4*)&zcat[(size_t)(r0 + lrow) * 64 + lk];
    float4 v1 = *(const float4*)&zcat[(size_t)(r0 + lrow) * 64 + lk + 4];
    float4 w0 = *(const float4*)&zcat[(size_t)(c0 + lrow) * 64 + 32 + lk];
    float4 w1 = *(const float4*)&zcat[(size_t)(c0 + lrow) * 64 + 32 + lk + 4];
    zsS[lk + 0][lrow] = v0.x; zsS[lk + 1][lrow] = v0.y; zsS[lk + 2][lrow] = v0.z; zsS[lk + 3][lrow] = v0.w;
    zsS[lk + 4][lrow] = v1.x; zsS[lk + 5][lrow] = v1.y; zsS[lk + 6][lrow] = v1.z; zsS[lk + 7][lrow] = v1.w;
    zdS[lk + 0][lrow] = w0.x; zdS[lk + 1][lrow] = w0.y; zdS[lk + 2][lrow] = w0.z; zdS[lk + 3][lrow] = w0.w;
    zdS[lk + 4][lrow] = w1.x; zdS[lk + 5][lrow] = w1.y; zdS[lk + 6][lrow] = w1.z; zdS[lk + 7][lrow] = w1.w;
    __syncthreads();

    float acc[4][4] = {};
#pragma unroll
    for (int k = 0; k < 32; k++) {
        const float4 a4 = *(const float4*)&zsS[k][ty * 4];
        const float4 b4 = *(const float4*)&zdS[k][tx * 4];
        const float aa[4] = {a4.x, a4.y, a4.z, a4.w};
        const float bb[4] = {b4.x, b4.y, b4.z, b4.w};
#pragma unroll
        for (int i = 0; i < 4; i++)
#pragma unroll
            for (int j = 0; j < 4; j++) acc[i][j] += aa[i] * bb[j];
    }

    float asum = 0.f, s1 = 0.f, s2 = 0.f;
#pragma unroll
    for (int i = 0; i < 4; i++) {
        const int r = r0 + ty * 4 + i;
        const float4 av4 = *(const float4*)&adj[(size_t)r * NND + c0 + tx * 4];
        const float av[4] = {av4.x, av4.y, av4.z, av4.w};
        float* drow = &dec[(size_t)r * NND + c0 + tx * 4];
#pragma unroll
        for (int j = 0; j < 4; j++) {
            float d = acc[i][j];
            drow[j] = d;  // scalar store: dec base (d_out+2) not 16B aligned
            float a = av[j];
            asum += a;
            s1 += a * lsigf(d);
            s2 += (1.f - a) * lsigf(-d);
        }
    }
    __shared__ float redA[256], redB[256], redC[256];
    redA[tid] = asum; redB[tid] = s1; redC[tid] = s2;
    __syncthreads();
    for (int o = 128; o > 0; o >>= 1) {
        if (tid < o) {
            redA[tid] += redA[tid + o];
            redB[tid] += redB[tid + o];
            redC[tid] += redC[tid + o];
        }
        __syncthreads();
    }
    if (tid == 0) {
        atomicAdd(&acc3[0], (double)redA[0]);
        atomicAdd(&acc3[1], (double)redB[0]);
        atomicAdd(&acc3[2], (double)redC[0]);
    }
}

// ---------------- finalize ----------------
__global__ void finalize_kernel(const double* __restrict__ accd, float* __restrict__ out) {
    if (threadIdx.x == 0 && blockIdx.x == 0) {
        const double nn2 = (double)NND * (double)NND;
        out[0] = (float)(0.5 * accd[0] / nn2);
        double nll = 0.0;
        for (int t = 0; t < NTS; ++t) {
            double s = accd[1 + 3 * t];
            double S1 = accd[2 + 3 * t];
            double S2 = accd[3 + 3 * t];
            double posw = (nn2 - s) / s;
            double norm = nn2 / ((nn2 - s) * 2.0);
            nll += norm * (-posw * S1 - S2) / nn2;
        }
        out[1] = (float)nll;
    }
}

// ---------------- host ----------------

extern "C" void kernel_launch(void* const* d_in, const int* in_sizes, int n_in,
                              void* d_out, int out_size, void* d_ws, size_t ws_size,
                              hipStream_t stream) {
    (void)in_sizes; (void)n_in; (void)out_size; (void)ws_size;

    const float* x_all = (const float*)d_in[0];
    const int* ei_all = (const int*)d_in[1];
    const float* adj_all = (const float*)d_in[2];
    const float* eps_s_all = (const float*)d_in[3];
    const float* eps_d_all = (const float*)d_in[4];
    const float* phi_x_w = (const float*)d_in[5];
    const float* phi_z_w = (const float*)d_in[6];
    const float* gru_xw0 = (const float*)d_in[7];
    const float* gru_xw1 = (const float*)d_in[8];
    const float* gru_hw = (const float*)d_in[9];
    const float* enc_w = (const float*)d_in[10];
    const float* enc_b = (const float*)d_in[11];
    const float* mean_w = (const float*)d_in[12];
    const float* mean_b = (const float*)d_in[13];
    const float* std_w = (const float*)d_in[14];
    const float* std_b = (const float*)d_in[15];
    const float* pri_w = (const float*)d_in[16];
    const float* pri_b = (const float*)d_in[17];
    const float* pri_mw = (const float*)d_in[18];
    const float* pri_mb = (const float*)d_in[19];
    const float* pri_sw = (const float*)d_in[20];
    const float* pri_sb = (const float*)d_in[21];
    float* out = (float*)d_out;

    // ---- workspace carve ----
    size_t off = 0;
    auto alloc = [&](size_t bytes) -> void* {
        void* p = (char*)d_ws + off;
        off = (off + bytes + 255) & ~(size_t)255;
        return p;
    };
    const size_t NH = (size_t)NND * HDI;
    const size_t NH2 = (size_t)NND * H2I;
    const size_t NZ = (size_t)NND * ZDI;

    float* hbase = (float*)alloc(4 * NH * 4);
    float* phi_x = (float*)alloc(NH * 4);
    float* phi_z = (float*)alloc(NH * 4);
    float* enc_s = (float*)alloc(NH * 4);
    float* enc_d = (float*)alloc(NH * 4);
    float* ginA = (float*)alloc(NH * 4);
    float* ginB = (float*)alloc(NH * 4);
    float* zg = (float*)alloc(NH * 4);      // also pri_s
    float* rg = (float*)alloc(NH * 4);      // also pri_d
    float* htmp = (float*)alloc(NH * 4);
    float* cat_pre = (float*)alloc(NH2 * 4);
    float* xpre = (float*)alloc(NH2 * 4);
    float* xpre1 = (float*)alloc(NH * 4);
    float* zcat = (float*)alloc((size_t)NND * 64 * 4);
    float* xw_s = (float*)alloc(NZ * 4);
    float* xw_d = (float*)alloc(NZ * 4);
    float* mean_s = (float*)alloc(NZ * 4);
    float* mean_d = (float*)alloc(NZ * 4);
    float* std_s = (float*)alloc(NZ * 4);
    float* std_d = (float*)alloc(NZ * 4);
    float* pm_s = (float*)alloc(NZ * 4);
    float* ps_s = (float*)alloc(NZ * 4);
    float* pm_d = (float*)alloc(NZ * 4);
    float* ps_d = (float*)alloc(NZ * 4);
    float* deg = (float*)alloc((size_t)NTS * NND * 4);
    float* dinv = (float*)alloc((size_t)NTS * NND * 4);
    int* counts = (int*)alloc(2 * (size_t)NTS * NND * 4);  // counts + cursor
    int* cursor = counts + (size_t)NTS * NND;
    int* offsets = (int*)alloc((size_t)NTS * (NND + 1) * 4);
    int* csrc = (int*)alloc((size_t)NTS * NED * 4);
    float* csrw = (float*)alloc((size_t)NTS * NED * 4);
    double* accd = (double*)alloc((1 + 3 * NTS) * 8);  // [0]=kld, then (asum,S1,S2) per t

    float* h0 = hbase;
    float* h1 = hbase + NH;
    float* nh0 = hbase + 2 * NH;
    float* nh1 = hbase + 3 * NH;

    hipMemsetAsync(hbase, 0, 2 * NH * 4, stream);
    hipMemsetAsync(counts, 0, 2 * (size_t)NTS * NND * 4, stream);
    hipMemsetAsync(accd, 0, (1 + 3 * NTS) * 8, stream);

    // CSR for all timesteps
    count_all<<<NTS * NED / 256, 256, 0, stream>>>(ei_all, counts);
    scan_all<<<NTS, 256, 0, stream>>>(counts, offsets, deg, dinv);
    fill_all<<<NTS * NED / 256, 256, 0, stream>>>(ei_all, offsets, cursor, dinv, csrc, csrw);

    const dim3 g1big(4, 32);   // single-output big gemm
    const dim3 g2big(8, 32);   // dual-output big gemm
    const dim3 gGather1(512, 1), gGather2(512, 2), gGather3(512, 3);

    for (int t = 0; t < NTS; ++t) {
        const float* x_t = x_all + (size_t)t * NND * XDI;
        const float* adj_t = adj_all + (size_t)t * NND * NND;
        const float* es_t = eps_s_all + (size_t)t * NND * ZDI;
        const float* ed_t = eps_d_all + (size_t)t * NND * ZDI;
        float* dec_t = out + 2 + (size_t)t * NND * NND;
        const int* off_t = offsets + (size_t)t * (NND + 1);
        const int* csrc_t = csrc + (size_t)t * NED;
        const float* csrw_t = csrw + (size_t)t * NED;
        const float* deg_t = deg + (size_t)t * NND;

        BigArgs ba = {};

        // phi_x = relu(x @ phi_x_w)
        ba = {}; ba.A1 = x_t; ba.K1 = XDI; ba.B1[0] = phi_x_w; ba.C[0] = phi_x;
        gemm_big<1, false, false, 0, false><<<g1big, 256, 0, stream>>>(ba);

        // cat_pre = gin([phi_x, h1])
        {
            GatherArgs ga = {};
            ga.in[0] = phi_x; ga.out[0] = cat_pre; ga.ostr[0] = H2I; ga.ooff[0] = 0;
            ga.in[1] = h1;    ga.out[1] = cat_pre; ga.ostr[1] = H2I; ga.ooff[1] = HDI;
            gather_multi<<<gGather2, 256, 0, stream>>>(ga, off_t, csrc_t);
        }

        // enc_s / enc_d (merged)
        ba = {}; ba.A1 = cat_pre; ba.K1 = H2I;
        ba.B1[0] = enc_w; ba.B1[1] = enc_w + (size_t)H2I * HDI;
        ba.bias[0] = enc_b; ba.bias[1] = enc_b + HDI;
        ba.C[0] = enc_s; ba.C[1] = enc_d;
        gemm_big<1, false, true, 0, true><<<g2big, 256, 0, stream>>>(ba);

        // xw_s/xw_d (small pair)
        {
            SmallArgs sa = {};
            sa.A[0] = enc_s; sa.B[0] = mean_w; sa.C[0] = xw_s; sa.act[0] = 0;
            sa.A[1] = enc_d; sa.B[1] = mean_w + (size_t)HDI * ZDI; sa.C[1] = xw_d; sa.act[1] = 0;
            small_gemm<<<dim3(256, 2), 256, 0, stream>>>(sa);
        }
        // mean_s/mean_d via GCN (pair)
        gcn_pair<<<dim3(256, 2), 256, 0, stream>>>(xw_s, xw_d, mean_b, off_t, csrc_t, csrw_t,
                                                   deg_t, mean_s, mean_d);
        // gin(enc_s), gin(enc_d)
        {
            GatherArgs ga = {};
            ga.in[0] = enc_s; ga.out[0] = ginA; ga.ostr[0] = HDI; ga.ooff[0] = 0;
            ga.in[1] = enc_d; ga.out[1] = ginB; ga.ostr[1] = HDI; ga.ooff[1] = 0;
            gather_multi<<<gGather2, 256, 0, stream>>>(ga, off_t, csrc_t);
        }
        // std_s/std_d (small pair, softplus)
        {
            SmallArgs sa = {};
            sa.A[0] = ginA; sa.B[0] = std_w; sa.bias[0] = std_b; sa.C[0] = std_s; sa.act[0] = 4;
            sa.A[1] = ginB; sa.B[1] = std_w + (size_t)HDI * ZDI; sa.bias[1] = std_b + ZDI;
            sa.C[1] = std_d; sa.act[1] = 4;
            small_gemm<<<dim3(256, 2), 256, 0, stream>>>(sa);
        }

        // priors: pri_s (zg), pri_d (rg) merged
        ba = {}; ba.A1 = h1; ba.K1 = HDI;
        ba.B1[0] = pri_w; ba.B1[1] = pri_w + (size_t)HDI * HDI;
        ba.bias[0] = pri_b; ba.bias[1] = pri_b + HDI;
        ba.C[0] = zg; ba.C[1] = rg;
        gemm_big<1, false, true, 0, true><<<g2big, 256, 0, stream>>>(ba);

        // pm_s, ps_s, pm_d, ps_d (small quad)
        {
            SmallArgs sa = {};
            sa.A[0] = zg; sa.B[0] = pri_mw; sa.bias[0] = pri_mb; sa.C[0] = pm_s; sa.act[0] = 0;
            sa.A[1] = zg; sa.B[1] = pri_sw; sa.bias[1] = pri_sb; sa.C[1] = ps_s; sa.act[1] = 4;
            sa.A[2] = rg; sa.B[2] = pri_mw + (size_t)HDI * ZDI; sa.bias[2] = pri_mb + ZDI;
            sa.C[2] = pm_d; sa.act[2] = 0;
            sa.A[3] = rg; sa.B[3] = pri_sw + (size_t)HDI * ZDI; sa.bias[3] = pri_sb + ZDI;
            sa.C[3] = ps_d; sa.act[3] = 4;
            small_gemm<<<dim3(256, 4), 256, 0, stream>>>(sa);
        }

        // z + kld
        zkld_kernel<<<(int)(NZ / 256), 256, 0, stream>>>(mean_s, std_s, es_t, mean_d, std_d,
                                                         ed_t, pm_s, ps_s, pm_d, ps_d, zcat,
                                                         &accd[0]);
        // phi_z = relu(zcat @ phi_z_w)
        ba = {}; ba.A1 = zcat; ba.K1 = 64; ba.B1[0] = phi_z_w; ba.C[0] = phi_z;
        gemm_big<1, false, false, 0, false><<<g1big, 256, 0, stream>>>(ba);
        // dec + bce partials
        dec_bce<<<dim3(NND / 64, NND / 64), 256, 0, stream>>>(zcat, adj_t, dec_t,
                                                              &accd[1 + 3 * t]);

        // gathers: xpre = gin([phi_x, phi_z]); ginA = gin(h0)
        {
            GatherArgs ga = {};
            ga.in[0] = phi_x; ga.out[0] = xpre; ga.ostr[0] = H2I; ga.ooff[0] = 0;
            ga.in[1] = phi_z; ga.out[1] = xpre; ga.ostr[1] = H2I; ga.ooff[1] = HDI;
            ga.in[2] = h0;    ga.out[2] = ginA; ga.ostr[2] = HDI; ga.ooff[2] = 0;
            gather_multi<<<gGather3, 256, 0, stream>>>(ga, off_t, csrc_t);
        }

        // GRU layer 0: z & r merged; htmp = sigmoid(r)*h0 fused
        ba = {}; ba.A1 = xpre; ba.K1 = H2I; ba.A2 = ginA; ba.K2 = HDI;
        ba.B1[0] = gru_xw0; ba.B1[1] = gru_xw0 + (size_t)H2I * HDI;
        ba.B2[0] = gru_hw; ba.B2[1] = gru_hw + (size_t)HDI * HDI;
        ba.C[0] = zg; ba.C[1] = htmp; ba.h = h0;
        gemm_big<2, true, false, 1, true><<<g2big, 256, 0, stream>>>(ba);
        // ginB = gin(htmp)
        {
            GatherArgs ga = {};
            ga.in[0] = htmp; ga.out[0] = ginB; ga.ostr[0] = HDI; ga.ooff[0] = 0;
            gather_multi<<<gGather1, 256, 0, stream>>>(ga, off_t, csrc_t);
        }
        // nh0 = zg*h0 + (1-zg)*tanh(xpre@Wh + ginB@Uh)
        ba = {}; ba.A1 = xpre; ba.K1 = H2I; ba.A2 = ginB; ba.K2 = HDI;
        ba.B1[0] = gru_xw0 + 2 * (size_t)H2I * HDI;
        ba.B2[0] = gru_hw + 2 * (size_t)HDI * HDI;
        ba.C[0] = nh0; ba.h = h0; ba.zgp = zg;
        gemm_big<0, true, false, 2, false><<<g1big, 256, 0, stream>>>(ba);

        // gathers: xpre1 = gin(nh0); ginA = gin(h1)
        {
            GatherArgs ga = {};
            ga.in[0] = nh0; ga.out[0] = xpre1; ga.ostr[0] = HDI; ga.ooff[0] = 0;
            ga.in[1] = h1;  ga.out[1] = ginA;  ga.ostr[1] = HDI; ga.ooff[1] = 0;
            gather_multi<<<gGather2, 256, 0, stream>>>(ga, off_t, csrc_t);
        }

        // GRU layer 1: z & r merged
        ba = {}; ba.A1 = xpre1; ba.K1 = HDI; ba.A2 = ginA; ba.K2 = HDI;
        ba.B1[0] = gru_xw1; ba.B1[1] = gru_xw1 + (size_t)HDI * HDI;
        ba.B2[0] = gru_hw + 3 * (size_t)HDI * HDI; ba.B2[1] = gru_hw + 4 * (size_t)HDI * HDI;
        ba.C[0] = zg; ba.C[1] = htmp; ba.h = h1;
        gemm_big<2, true, false, 1, true><<<g2big, 256, 0, stream>>>(ba);
        // ginB = gin(htmp)
        {
            GatherArgs ga = {};
            ga.in[0] = htmp; ga.out[0] = ginB; ga.ostr[0] = HDI; ga.ooff[0] = 0;
            gather_multi<<<gGather1, 256, 0, stream>>>(ga, off_t, csrc_t);
        }
        // nh1
        ba = {}; ba.A1 = xpre1; ba.K1 = HDI; ba.A2 = ginB; ba.K2 = HDI;
        ba.B1[0] = gru_xw1 + 2 * (size_t)HDI * HDI;
        ba.B2[0] = gru_hw + 5 * (size_t)HDI * HDI;
        ba.C[0] = nh1; ba.h = h1; ba.zgp = zg;
        gemm_big<0, true, false, 2, false><<<g1big, 256, 0, stream>>>(ba);

        // swap ping-pong
        float* tp;
        tp = h0; h0 = nh0; nh0 = tp;
        tp = h1; h1 = nh1; nh1 = tp;
    }

    finalize_kernel<<<1, 64, 0, stream>>>(accd, out);
}